// Round 1
// baseline (210.699 us; speedup 1.0000x reference)
//
#include <hip/hip_runtime.h>

// TimeConvX: truncated temporal spectral conv (FNO-style), T=16, M=3 modes, C=8.
// out[t,b,c] = v[t,b,c] + irfft( einsum('bim,iom->bom', rfft(v)[..,:3], w) )[b,c,t]
// One thread per batch element b = bn*3+d (393216 total). Memory-bound:
// 402.7 MB in + 402.7 MB out -> ideal ~128 us @ 6.3 TB/s.

#define TT 16
#define CC 8
#define MM 3
#define NBATCH (131072 * 3)          // 393216
#define TSTRIDE (131072 * 3 * 8)     // 3145728 floats between time steps

// cos/sin(2*pi*m*t/16) tables, folded at compile time via full unroll.
static constexpr float C1[TT] = {
     1.0f,  0.9238795325f,  0.7071067812f,  0.3826834324f,
     0.0f, -0.3826834324f, -0.7071067812f, -0.9238795325f,
    -1.0f, -0.9238795325f, -0.7071067812f, -0.3826834324f,
     0.0f,  0.3826834324f,  0.7071067812f,  0.9238795325f };
static constexpr float S1[TT] = {
     0.0f,  0.3826834324f,  0.7071067812f,  0.9238795325f,
     1.0f,  0.9238795325f,  0.7071067812f,  0.3826834324f,
     0.0f, -0.3826834324f, -0.7071067812f, -0.9238795325f,
    -1.0f, -0.9238795325f, -0.7071067812f, -0.3826834324f };
static constexpr float C2[TT] = {
     1.0f,  0.7071067812f,  0.0f, -0.7071067812f,
    -1.0f, -0.7071067812f,  0.0f,  0.7071067812f,
     1.0f,  0.7071067812f,  0.0f, -0.7071067812f,
    -1.0f, -0.7071067812f,  0.0f,  0.7071067812f };
static constexpr float S2[TT] = {
     0.0f,  0.7071067812f,  1.0f,  0.7071067812f,
     0.0f, -0.7071067812f, -1.0f, -0.7071067812f,
     0.0f,  0.7071067812f,  1.0f,  0.7071067812f,
     0.0f, -0.7071067812f, -1.0f, -0.7071067812f };

__global__ __launch_bounds__(256, 2) void timeconvx_kernel(
    const float* __restrict__ v,
    const float* __restrict__ wr,
    const float* __restrict__ wi,
    float* __restrict__ out)
{
    __shared__ float s_wr[CC * CC * MM];
    __shared__ float s_wi[CC * CC * MM];
    const int tid = threadIdx.x;
    if (tid < CC * CC * MM) {
        s_wr[tid] = wr[tid];
        s_wi[tid] = wi[tid];
    }
    __syncthreads();

    const int b = blockIdx.x * 256 + tid;    // grid sized exactly: no bounds check
    const float* __restrict__ base = v + (size_t)b * CC;

    // ---- load x[t][c]: 2x float4 per t, coalesced (lane stride 32B) ----
    float x[TT][CC];
    #pragma unroll
    for (int t = 0; t < TT; ++t) {
        const float4* p = (const float4*)(base + (size_t)t * TSTRIDE);
        float4 a0 = p[0];
        float4 a1 = p[1];
        x[t][0] = a0.x; x[t][1] = a0.y; x[t][2] = a0.z; x[t][3] = a0.w;
        x[t][4] = a1.x; x[t][5] = a1.y; x[t][6] = a1.z; x[t][7] = a1.w;
    }

    // ---- forward: X[i][m] for m=0,1,2 (m=0 imag is 0) ----
    // rfft: X = sum_t x * exp(-2*pi*i*m*t/16) -> Xr = sum x*cos, Xi = -sum x*sin
    float Xr0[CC], Xr1[CC], Xi1[CC], Xr2[CC], Xi2[CC];
    #pragma unroll
    for (int i = 0; i < CC; ++i) { Xr0[i]=0.f; Xr1[i]=0.f; Xi1[i]=0.f; Xr2[i]=0.f; Xi2[i]=0.f; }
    #pragma unroll
    for (int t = 0; t < TT; ++t) {
        const float c1 = C1[t], s1 = S1[t], c2 = C2[t], s2 = S2[t];
        #pragma unroll
        for (int i = 0; i < CC; ++i) {
            const float xv = x[t][i];
            Xr0[i] += xv;
            Xr1[i] += xv * c1;
            Xi1[i] -= xv * s1;
            Xr2[i] += xv * c2;
            Xi2[i] -= xv * s2;
        }
    }

    // ---- channel mix: F[o][m] = sum_i X[i][m] * (wr[i][o][m] + i*wi[i][o][m])
    // irfft ignores Im(F[.,0]) (pocketfft c2r drops imag of DC bin) -> skip it.
    // Fold irfft scaling: mode0 -> 1/16, modes 1,2 -> 2/16.
    float Fr0[CC], Fr1[CC], Fi1[CC], Fr2[CC], Fi2[CC];
    #pragma unroll
    for (int o = 0; o < CC; ++o) {
        float fr0 = 0.f, fr1 = 0.f, fi1 = 0.f, fr2 = 0.f, fi2 = 0.f;
        #pragma unroll
        for (int i = 0; i < CC; ++i) {
            const int w3 = (i * CC + o) * MM;
            const float wr0 = s_wr[w3 + 0];
            const float wr1 = s_wr[w3 + 1], wi1 = s_wi[w3 + 1];
            const float wr2 = s_wr[w3 + 2], wi2 = s_wi[w3 + 2];
            fr0 += Xr0[i] * wr0;
            fr1 += Xr1[i] * wr1 - Xi1[i] * wi1;
            fi1 += Xr1[i] * wi1 + Xi1[i] * wr1;
            fr2 += Xr2[i] * wr2 - Xi2[i] * wi2;
            fi2 += Xr2[i] * wi2 + Xi2[i] * wr2;
        }
        Fr0[o] = fr0 * 0.0625f;
        Fr1[o] = fr1 * 0.125f;
        Fi1[o] = fi1 * 0.125f;
        Fr2[o] = fr2 * 0.125f;
        Fi2[o] = fi2 * 0.125f;
    }

    // ---- inverse + residual + store ----
    // y[o,t] = Fr0 + c1*Fr1 - s1*Fi1 + c2*Fr2 - s2*Fi2   (scales pre-folded)
    float* __restrict__ obase = out + (size_t)b * CC;
    #pragma unroll
    for (int t = 0; t < TT; ++t) {
        const float c1 = C1[t], s1 = S1[t], c2 = C2[t], s2 = S2[t];
        float yv[CC];
        #pragma unroll
        for (int o = 0; o < CC; ++o) {
            float y = Fr0[o];
            y += c1 * Fr1[o];
            y -= s1 * Fi1[o];
            y += c2 * Fr2[o];
            y -= s2 * Fi2[o];
            yv[o] = x[t][o] + y;
        }
        float4* p = (float4*)(obase + (size_t)t * TSTRIDE);
        p[0] = make_float4(yv[0], yv[1], yv[2], yv[3]);
        p[1] = make_float4(yv[4], yv[5], yv[6], yv[7]);
    }
}

extern "C" void kernel_launch(void* const* d_in, const int* in_sizes, int n_in,
                              void* d_out, int out_size, void* d_ws, size_t ws_size,
                              hipStream_t stream) {
    const float* v  = (const float*)d_in[0];
    const float* wr = (const float*)d_in[1];
    const float* wi = (const float*)d_in[2];
    float* out = (float*)d_out;

    const int threads = 256;
    const int blocks = NBATCH / threads;   // 393216 / 256 = 1536, exact
    timeconvx_kernel<<<blocks, threads, 0, stream>>>(v, wr, wi, out);
}

// Round 3
// 195.362 us; speedup vs baseline: 1.0785x; 1.0785x over previous
//
#include <hip/hip_runtime.h>

// TimeConvX: truncated temporal spectral conv (FNO-style), T=16, M=3 modes, C=8.
// out[t,b,c] = v[t,b,c] + irfft( einsum('bim,iom->bom', rfft(v)[..,:3], w) )
// R2: same as R1 (2 threads/batch elem, shfl_xor partner exchange, bf16
// residual, NT stores) but with native clang vector type for the NT builtin.

#define TT 16
#define CC 8
#define MM 3
#define NBATCH (131072 * 3)            // 393216 batch elements
#define T4STRIDE (131072 * 3 * 8 / 4)  // float4 stride between time steps = 786432

typedef float f4 __attribute__((ext_vector_type(4)));   // native vector: NT-store OK

static constexpr float C1[TT] = {
     1.0f,  0.9238795325f,  0.7071067812f,  0.3826834324f,
     0.0f, -0.3826834324f, -0.7071067812f, -0.9238795325f,
    -1.0f, -0.9238795325f, -0.7071067812f, -0.3826834324f,
     0.0f,  0.3826834324f,  0.7071067812f,  0.9238795325f };
static constexpr float S1[TT] = {
     0.0f,  0.3826834324f,  0.7071067812f,  0.9238795325f,
     1.0f,  0.9238795325f,  0.7071067812f,  0.3826834324f,
     0.0f, -0.3826834324f, -0.7071067812f, -0.9238795325f,
    -1.0f, -0.9238795325f, -0.7071067812f, -0.3826834324f };
static constexpr float C2[TT] = {
     1.0f,  0.7071067812f,  0.0f, -0.7071067812f,
    -1.0f, -0.7071067812f,  0.0f,  0.7071067812f,
     1.0f,  0.7071067812f,  0.0f, -0.7071067812f,
    -1.0f, -0.7071067812f,  0.0f,  0.7071067812f };
static constexpr float S2[TT] = {
     0.0f,  0.7071067812f,  1.0f,  0.7071067812f,
     0.0f, -0.7071067812f, -1.0f, -0.7071067812f,
     0.0f,  0.7071067812f,  1.0f,  0.7071067812f,
     0.0f, -0.7071067812f, -1.0f, -0.7071067812f };

// pack two fp32 -> one u32 of 2 bf16 (round-to-nearest-ish)
__device__ __forceinline__ unsigned pk2(float a, float b) {
    unsigned ua = __float_as_uint(a) + 0x8000u;
    unsigned ub = __float_as_uint(b) + 0x8000u;
    return (ua >> 16) | (ub & 0xFFFF0000u);
}
__device__ __forceinline__ float upLo(unsigned p) { return __uint_as_float(p << 16); }
__device__ __forceinline__ float upHi(unsigned p) { return __uint_as_float(p & 0xFFFF0000u); }

__global__ __launch_bounds__(256, 4) void timeconvx_kernel(
    const f4* __restrict__ v4,
    const float* __restrict__ wr,
    const float* __restrict__ wi,
    f4* __restrict__ out4)
{
    __shared__ float s_wr[CC * CC * MM];
    __shared__ float s_wi[CC * CC * MM];
    const int tid = threadIdx.x;
    if (tid < CC * CC * MM) {
        s_wr[tid] = wr[tid];
        s_wi[tid] = wi[tid];
    }
    __syncthreads();

    const int g = blockIdx.x * 256 + tid;   // [0, 2*NBATCH), exact grid
    const int half = g & 1;                 // 0: channels 0-3, 1: channels 4-7
    const f4* __restrict__ vp = v4 + g;

    // ---- load + forward transform (own 4 channels), keep bf16 residual ----
    unsigned xb[TT][2];
    float Xr0[4], Xr1[4], Xi1[4], Xr2[4], Xi2[4];
    #pragma unroll
    for (int j = 0; j < 4; ++j) { Xr0[j]=0.f; Xr1[j]=0.f; Xi1[j]=0.f; Xr2[j]=0.f; Xi2[j]=0.f; }
    #pragma unroll
    for (int t = 0; t < TT; ++t) {
        const f4 a = vp[(size_t)t * T4STRIDE];
        const float c1 = C1[t], s1 = S1[t], c2 = C2[t], s2 = S2[t];
        #pragma unroll
        for (int j = 0; j < 4; ++j) {
            const float xv = a[j];
            Xr0[j] += xv;
            Xr1[j] += xv * c1;
            Xi1[j] -= xv * s1;
            Xr2[j] += xv * c2;
            Xi2[j] -= xv * s2;
        }
        xb[t][0] = pk2(a[0], a[1]);
        xb[t][1] = pk2(a[2], a[3]);
    }

    // ---- exchange partner lane's spectra (other 4 channels) ----
    float Yr0[4], Yr1[4], Yi1[4], Yr2[4], Yi2[4];
    #pragma unroll
    for (int j = 0; j < 4; ++j) {
        Yr0[j] = __shfl_xor(Xr0[j], 1, 64);
        Yr1[j] = __shfl_xor(Xr1[j], 1, 64);
        Yi1[j] = __shfl_xor(Xi1[j], 1, 64);
        Yr2[j] = __shfl_xor(Xr2[j], 1, 64);
        Yi2[j] = __shfl_xor(Xi2[j], 1, 64);
    }
    // channels 0-3 (AL) / 4-7 (AH), branchless select, compile-time indices
    float ALr0[4], ALr1[4], ALi1[4], ALr2[4], ALi2[4];
    float AHr0[4], AHr1[4], AHi1[4], AHr2[4], AHi2[4];
    #pragma unroll
    for (int j = 0; j < 4; ++j) {
        ALr0[j] = half ? Yr0[j] : Xr0[j];  AHr0[j] = half ? Xr0[j] : Yr0[j];
        ALr1[j] = half ? Yr1[j] : Xr1[j];  AHr1[j] = half ? Xr1[j] : Yr1[j];
        ALi1[j] = half ? Yi1[j] : Xi1[j];  AHi1[j] = half ? Xi1[j] : Yi1[j];
        ALr2[j] = half ? Yr2[j] : Xr2[j];  AHr2[j] = half ? Xr2[j] : Yr2[j];
        ALi2[j] = half ? Yi2[j] : Xi2[j];  AHi2[j] = half ? Xi2[j] : Yi2[j];
    }

    // ---- channel mix for own 4 output channels o = half*4 + j ----
    const int obase = half * 4;
    float Fr0[4], Fr1[4], Fi1[4], Fr2[4], Fi2[4];
    #pragma unroll
    for (int j = 0; j < 4; ++j) {
        const int o3 = (obase + j) * MM;
        float fr0 = 0.f, fr1 = 0.f, fi1 = 0.f, fr2 = 0.f, fi2 = 0.f;
        #pragma unroll
        for (int i = 0; i < 4; ++i) {       // input channels 0-3
            const int w3 = i * CC * MM + o3;
            const float w0 = s_wr[w3 + 0];
            const float w1r = s_wr[w3 + 1], w1i = s_wi[w3 + 1];
            const float w2r = s_wr[w3 + 2], w2i = s_wi[w3 + 2];
            fr0 += ALr0[i] * w0;
            fr1 += ALr1[i] * w1r - ALi1[i] * w1i;
            fi1 += ALr1[i] * w1i + ALi1[i] * w1r;
            fr2 += ALr2[i] * w2r - ALi2[i] * w2i;
            fi2 += ALr2[i] * w2i + ALi2[i] * w2r;
        }
        #pragma unroll
        for (int i = 0; i < 4; ++i) {       // input channels 4-7
            const int w3 = (i + 4) * CC * MM + o3;
            const float w0 = s_wr[w3 + 0];
            const float w1r = s_wr[w3 + 1], w1i = s_wi[w3 + 1];
            const float w2r = s_wr[w3 + 2], w2i = s_wi[w3 + 2];
            fr0 += AHr0[i] * w0;
            fr1 += AHr1[i] * w1r - AHi1[i] * w1i;
            fi1 += AHr1[i] * w1i + AHi1[i] * w1r;
            fr2 += AHr2[i] * w2r - AHi2[i] * w2i;
            fi2 += AHr2[i] * w2i + AHi2[i] * w2r;
        }
        Fr0[j] = fr0 * 0.0625f;   // 1/16 (DC); imag of DC dropped by irfft
        Fr1[j] = fr1 * 0.125f;    // 2/16 (modes 1,2)
        Fi1[j] = fi1 * 0.125f;
        Fr2[j] = fr2 * 0.125f;
        Fi2[j] = fi2 * 0.125f;
    }

    // ---- inverse + residual + nontemporal store ----
    f4* __restrict__ op = out4 + g;
    #pragma unroll
    for (int t = 0; t < TT; ++t) {
        const float c1 = C1[t], s1 = S1[t], c2 = C2[t], s2 = S2[t];
        f4 r;
        #pragma unroll
        for (int j = 0; j < 4; ++j) {
            float yy = Fr0[j];
            yy += c1 * Fr1[j];
            yy -= s1 * Fi1[j];
            yy += c2 * Fr2[j];
            yy -= s2 * Fi2[j];
            const unsigned p = xb[t][j >> 1];
            const float xres = (j & 1) ? upHi(p) : upLo(p);
            r[j] = xres + yy;
        }
        __builtin_nontemporal_store(r, op + (size_t)t * T4STRIDE);
    }
}

extern "C" void kernel_launch(void* const* d_in, const int* in_sizes, int n_in,
                              void* d_out, int out_size, void* d_ws, size_t ws_size,
                              hipStream_t stream) {
    const f4* v4     = (const f4*)d_in[0];
    const float* wr  = (const float*)d_in[1];
    const float* wi  = (const float*)d_in[2];
    f4* out4 = (f4*)d_out;

    const int threads = 256;
    const int blocks = (2 * NBATCH) / threads;   // 786432 / 256 = 3072, exact
    timeconvx_kernel<<<blocks, threads, 0, stream>>>(v4, wr, wi, out4);
}

// Round 4
// 194.019 us; speedup vs baseline: 1.0860x; 1.0069x over previous
//
#include <hip/hip_runtime.h>

// TimeConvX: truncated temporal spectral conv (FNO-style), T=16, M=3 modes, C=8.
// out[t,b,c] = v[t,b,c] + irfft( einsum('bim,iom->bom', rfft(v)[..,:3], w) )
// R4: latency/MLP fix. 2 threads per batch element (4 ch each, lane-contiguous
// 16B accesses). All 16 t-slice loads issued into registers BEFORE compute
// (16 outstanding dwordx4/thread). XCD-bijective block swizzle. Plain stores.
// Exact fp32 residual (a[] stays live through the store loop).

#define TT 16
#define CC 8
#define MM 3
#define NBATCH (131072 * 3)            // 393216 batch elements
#define T4STRIDE (131072 * 3 * 8 / 4)  // float4 stride between t slices = 786432
#define NBLK 3072                      // (2*NBATCH)/256
#define NXCD 8
#define BLK_PER_XCD (NBLK / NXCD)      // 384

typedef float f4 __attribute__((ext_vector_type(4)));

static constexpr float C1[TT] = {
     1.0f,  0.9238795325f,  0.7071067812f,  0.3826834324f,
     0.0f, -0.3826834324f, -0.7071067812f, -0.9238795325f,
    -1.0f, -0.9238795325f, -0.7071067812f, -0.3826834324f,
     0.0f,  0.3826834324f,  0.7071067812f,  0.9238795325f };
static constexpr float S1[TT] = {
     0.0f,  0.3826834324f,  0.7071067812f,  0.9238795325f,
     1.0f,  0.9238795325f,  0.7071067812f,  0.3826834324f,
     0.0f, -0.3826834324f, -0.7071067812f, -0.9238795325f,
    -1.0f, -0.9238795325f, -0.7071067812f, -0.3826834324f };
static constexpr float C2[TT] = {
     1.0f,  0.7071067812f,  0.0f, -0.7071067812f,
    -1.0f, -0.7071067812f,  0.0f,  0.7071067812f,
     1.0f,  0.7071067812f,  0.0f, -0.7071067812f,
    -1.0f, -0.7071067812f,  0.0f,  0.7071067812f };
static constexpr float S2[TT] = {
     0.0f,  0.7071067812f,  1.0f,  0.7071067812f,
     0.0f, -0.7071067812f, -1.0f, -0.7071067812f,
     0.0f,  0.7071067812f,  1.0f,  0.7071067812f,
     0.0f, -0.7071067812f, -1.0f, -0.7071067812f };

__global__ __launch_bounds__(256, 4) void timeconvx_kernel(
    const f4* __restrict__ v4,
    const float* __restrict__ wr,
    const float* __restrict__ wi,
    f4* __restrict__ out4)
{
    __shared__ float s_wr[CC * CC * MM];
    __shared__ float s_wi[CC * CC * MM];
    const int tid = threadIdx.x;
    if (tid < CC * CC * MM) {
        s_wr[tid] = wr[tid];
        s_wi[tid] = wi[tid];
    }

    // XCD-bijective swizzle: XCD k owns logical blocks [k*384, (k+1)*384)
    // -> each XCD streams a contiguous 1/8 of every t-slice (L2/channel locality).
    const int bid = blockIdx.x;
    const int lbid = (bid & (NXCD - 1)) * BLK_PER_XCD + (bid >> 3);
    const int g = lbid * 256 + tid;        // [0, 2*NBATCH)
    const int half = g & 1;                // 0: ch 0-3, 1: ch 4-7
    const f4* __restrict__ vp = v4 + g;

    // ---- issue ALL 16 slice loads first: 16 outstanding dwordx4 per thread ----
    f4 a[TT];
    #pragma unroll
    for (int t = 0; t < TT; ++t)
        a[t] = vp[(size_t)t * T4STRIDE];

    __syncthreads();   // weights visible (placed after load issue to overlap)

    // ---- forward: X[j][m], m=0,1,2 (m=0 imag = 0) ----
    float Xr0[4], Xr1[4], Xi1[4], Xr2[4], Xi2[4];
    #pragma unroll
    for (int j = 0; j < 4; ++j) { Xr0[j]=0.f; Xr1[j]=0.f; Xi1[j]=0.f; Xr2[j]=0.f; Xi2[j]=0.f; }
    #pragma unroll
    for (int t = 0; t < TT; ++t) {
        const float c1 = C1[t], s1 = S1[t], c2 = C2[t], s2 = S2[t];
        #pragma unroll
        for (int j = 0; j < 4; ++j) {
            const float xv = a[t][j];
            Xr0[j] += xv;
            Xr1[j] += xv * c1;
            Xi1[j] -= xv * s1;
            Xr2[j] += xv * c2;
            Xi2[j] -= xv * s2;
        }
    }

    // ---- exchange partner lane's spectra (other 4 channels) ----
    float Yr0[4], Yr1[4], Yi1[4], Yr2[4], Yi2[4];
    #pragma unroll
    for (int j = 0; j < 4; ++j) {
        Yr0[j] = __shfl_xor(Xr0[j], 1, 64);
        Yr1[j] = __shfl_xor(Xr1[j], 1, 64);
        Yi1[j] = __shfl_xor(Xi1[j], 1, 64);
        Yr2[j] = __shfl_xor(Xr2[j], 1, 64);
        Yi2[j] = __shfl_xor(Xi2[j], 1, 64);
    }
    float ALr0[4], ALr1[4], ALi1[4], ALr2[4], ALi2[4];
    float AHr0[4], AHr1[4], AHi1[4], AHr2[4], AHi2[4];
    #pragma unroll
    for (int j = 0; j < 4; ++j) {
        ALr0[j] = half ? Yr0[j] : Xr0[j];  AHr0[j] = half ? Xr0[j] : Yr0[j];
        ALr1[j] = half ? Yr1[j] : Xr1[j];  AHr1[j] = half ? Xr1[j] : Yr1[j];
        ALi1[j] = half ? Yi1[j] : Xi1[j];  AHi1[j] = half ? Xi1[j] : Yi1[j];
        ALr2[j] = half ? Yr2[j] : Xr2[j];  AHr2[j] = half ? Xr2[j] : Yr2[j];
        ALi2[j] = half ? Yi2[j] : Xi2[j];  AHi2[j] = half ? Xi2[j] : Yi2[j];
    }

    // ---- channel mix for own 4 output channels o = half*4 + j ----
    const int obase = half * 4;
    float Fr0[4], Fr1[4], Fi1[4], Fr2[4], Fi2[4];
    #pragma unroll
    for (int j = 0; j < 4; ++j) {
        const int o3 = (obase + j) * MM;
        float fr0 = 0.f, fr1 = 0.f, fi1 = 0.f, fr2 = 0.f, fi2 = 0.f;
        #pragma unroll
        for (int i = 0; i < 4; ++i) {       // input channels 0-3
            const int w3 = i * CC * MM + o3;
            const float w0 = s_wr[w3 + 0];
            const float w1r = s_wr[w3 + 1], w1i = s_wi[w3 + 1];
            const float w2r = s_wr[w3 + 2], w2i = s_wi[w3 + 2];
            fr0 += ALr0[i] * w0;
            fr1 += ALr1[i] * w1r - ALi1[i] * w1i;
            fi1 += ALr1[i] * w1i + ALi1[i] * w1r;
            fr2 += ALr2[i] * w2r - ALi2[i] * w2i;
            fi2 += ALr2[i] * w2i + ALi2[i] * w2r;
        }
        #pragma unroll
        for (int i = 0; i < 4; ++i) {       // input channels 4-7
            const int w3 = (i + 4) * CC * MM + o3;
            const float w0 = s_wr[w3 + 0];
            const float w1r = s_wr[w3 + 1], w1i = s_wi[w3 + 1];
            const float w2r = s_wr[w3 + 2], w2i = s_wi[w3 + 2];
            fr0 += AHr0[i] * w0;
            fr1 += AHr1[i] * w1r - AHi1[i] * w1i;
            fi1 += AHr1[i] * w1i + AHi1[i] * w1r;
            fr2 += AHr2[i] * w2r - AHi2[i] * w2i;
            fi2 += AHr2[i] * w2i + AHi2[i] * w2r;
        }
        Fr0[j] = fr0 * 0.0625f;   // 1/16 (DC); imag of DC dropped by irfft
        Fr1[j] = fr1 * 0.125f;    // 2/16 (modes 1,2)
        Fi1[j] = fi1 * 0.125f;
        Fr2[j] = fr2 * 0.125f;
        Fi2[j] = fi2 * 0.125f;
    }

    // ---- inverse + exact fp32 residual + plain store ----
    f4* __restrict__ op = out4 + g;
    #pragma unroll
    for (int t = 0; t < TT; ++t) {
        const float c1 = C1[t], s1 = S1[t], c2 = C2[t], s2 = S2[t];
        f4 r;
        #pragma unroll
        for (int j = 0; j < 4; ++j) {
            float yy = Fr0[j];
            yy += c1 * Fr1[j];
            yy -= s1 * Fi1[j];
            yy += c2 * Fr2[j];
            yy -= s2 * Fi2[j];
            r[j] = a[t][j] + yy;
        }
        op[(size_t)t * T4STRIDE] = r;
    }
}

extern "C" void kernel_launch(void* const* d_in, const int* in_sizes, int n_in,
                              void* d_out, int out_size, void* d_ws, size_t ws_size,
                              hipStream_t stream) {
    const f4* v4     = (const f4*)d_in[0];
    const float* wr  = (const float*)d_in[1];
    const float* wi  = (const float*)d_in[2];
    f4* out4 = (f4*)d_out;

    const int threads = 256;
    timeconvx_kernel<<<NBLK, threads, 0, stream>>>(v4, wr, wi, out4);
}

// Round 5
// 129.430 us; speedup vs baseline: 1.6279x; 1.4990x over previous
//
#include <hip/hip_runtime.h>

// TimeConvX: truncated temporal spectral conv (FNO-style), T=16, M=3 modes, C=8.
// out[t,b,c] = v[t,b,c] + irfft( einsum('bim,iom->bom', rfft(v)[..,:3], w) )
// R5: force 16-deep load MLP. All 16 strided dwordx4 loads issued BEFORE any
// compute (sched_barrier pin), consumed in issue order. Residual held as packed
// bf16 so a[16] dies after the transform (VGPR cap 170 via launch_bounds(256,3),
// so the compiler keeps all 16 load dests live instead of re-loading v like R4
// did at VGPR=64 -> FETCH 1.4x). XCD-bijective block swizzle kept.

#define TT 16
#define CC 8
#define MM 3
#define NBATCH (131072 * 3)            // 393216 batch elements
#define T4STRIDE (131072 * 3 * 8 / 4)  // float4 stride between t slices = 786432
#define NBLK 3072                      // (2*NBATCH)/256
#define NXCD 8
#define BLK_PER_XCD (NBLK / NXCD)      // 384

typedef float f4 __attribute__((ext_vector_type(4)));

static constexpr float C1[TT] = {
     1.0f,  0.9238795325f,  0.7071067812f,  0.3826834324f,
     0.0f, -0.3826834324f, -0.7071067812f, -0.9238795325f,
    -1.0f, -0.9238795325f, -0.7071067812f, -0.3826834324f,
     0.0f,  0.3826834324f,  0.7071067812f,  0.9238795325f };
static constexpr float S1[TT] = {
     0.0f,  0.3826834324f,  0.7071067812f,  0.9238795325f,
     1.0f,  0.9238795325f,  0.7071067812f,  0.3826834324f,
     0.0f, -0.3826834324f, -0.7071067812f, -0.9238795325f,
    -1.0f, -0.9238795325f, -0.7071067812f, -0.3826834324f };
static constexpr float C2[TT] = {
     1.0f,  0.7071067812f,  0.0f, -0.7071067812f,
    -1.0f, -0.7071067812f,  0.0f,  0.7071067812f,
     1.0f,  0.7071067812f,  0.0f, -0.7071067812f,
    -1.0f, -0.7071067812f,  0.0f,  0.7071067812f };
static constexpr float S2[TT] = {
     0.0f,  0.7071067812f,  1.0f,  0.7071067812f,
     0.0f, -0.7071067812f, -1.0f, -0.7071067812f,
     0.0f,  0.7071067812f,  1.0f,  0.7071067812f,
     0.0f, -0.7071067812f, -1.0f, -0.7071067812f };

// pack two fp32 -> one u32 of 2 bf16
__device__ __forceinline__ unsigned pk2(float a, float b) {
    unsigned ua = __float_as_uint(a) + 0x8000u;
    unsigned ub = __float_as_uint(b) + 0x8000u;
    return (ua >> 16) | (ub & 0xFFFF0000u);
}
__device__ __forceinline__ float upLo(unsigned p) { return __uint_as_float(p << 16); }
__device__ __forceinline__ float upHi(unsigned p) { return __uint_as_float(p & 0xFFFF0000u); }

__global__ __launch_bounds__(256, 3) void timeconvx_kernel(
    const f4* __restrict__ v4,
    const float* __restrict__ wr,
    const float* __restrict__ wi,
    f4* __restrict__ out4)
{
    __shared__ float s_wr[CC * CC * MM];
    __shared__ float s_wi[CC * CC * MM];
    const int tid = threadIdx.x;
    if (tid < CC * CC * MM) {
        s_wr[tid] = wr[tid];
        s_wi[tid] = wi[tid];
    }

    // XCD-bijective swizzle: each XCD streams a contiguous 1/8 of every t-slice.
    const int bid = blockIdx.x;
    const int lbid = (bid & (NXCD - 1)) * BLK_PER_XCD + (bid >> 3);
    const int g = lbid * 256 + tid;        // [0, 2*NBATCH)
    const int half = g & 1;                // 0: ch 0-3, 1: ch 4-7
    const f4* __restrict__ vp = v4 + g;

    // ---- phase 1: issue ALL 16 slice loads (16 outstanding dwordx4/thread) ----
    f4 a[TT];
    #pragma unroll
    for (int t = 0; t < TT; ++t)
        a[t] = vp[(size_t)t * T4STRIDE];
    __builtin_amdgcn_sched_barrier(0);   // nothing moves across: loads all issued

    // ---- phase 2: consume in issue order; a[t] dies here (bf16 residual) ----
    unsigned xb[TT][2];
    float Xr0[4], Xr1[4], Xi1[4], Xr2[4], Xi2[4];
    #pragma unroll
    for (int j = 0; j < 4; ++j) { Xr0[j]=0.f; Xr1[j]=0.f; Xi1[j]=0.f; Xr2[j]=0.f; Xi2[j]=0.f; }
    #pragma unroll
    for (int t = 0; t < TT; ++t) {
        const float c1 = C1[t], s1 = S1[t], c2 = C2[t], s2 = S2[t];
        #pragma unroll
        for (int j = 0; j < 4; ++j) {
            const float xv = a[t][j];
            Xr0[j] += xv;
            Xr1[j] += xv * c1;
            Xi1[j] -= xv * s1;
            Xr2[j] += xv * c2;
            Xi2[j] -= xv * s2;
        }
        xb[t][0] = pk2(a[t][0], a[t][1]);
        xb[t][1] = pk2(a[t][2], a[t][3]);
    }

    __syncthreads();   // weights visible

    // ---- exchange partner lane's spectra (other 4 channels) ----
    float Yr0[4], Yr1[4], Yi1[4], Yr2[4], Yi2[4];
    #pragma unroll
    for (int j = 0; j < 4; ++j) {
        Yr0[j] = __shfl_xor(Xr0[j], 1, 64);
        Yr1[j] = __shfl_xor(Xr1[j], 1, 64);
        Yi1[j] = __shfl_xor(Xi1[j], 1, 64);
        Yr2[j] = __shfl_xor(Xr2[j], 1, 64);
        Yi2[j] = __shfl_xor(Xi2[j], 1, 64);
    }
    float ALr0[4], ALr1[4], ALi1[4], ALr2[4], ALi2[4];
    float AHr0[4], AHr1[4], AHi1[4], AHr2[4], AHi2[4];
    #pragma unroll
    for (int j = 0; j < 4; ++j) {
        ALr0[j] = half ? Yr0[j] : Xr0[j];  AHr0[j] = half ? Xr0[j] : Yr0[j];
        ALr1[j] = half ? Yr1[j] : Xr1[j];  AHr1[j] = half ? Xr1[j] : Yr1[j];
        ALi1[j] = half ? Yi1[j] : Xi1[j];  AHi1[j] = half ? Xi1[j] : Yi1[j];
        ALr2[j] = half ? Yr2[j] : Xr2[j];  AHr2[j] = half ? Xr2[j] : Yr2[j];
        ALi2[j] = half ? Yi2[j] : Xi2[j];  AHi2[j] = half ? Xi2[j] : Yi2[j];
    }

    // ---- channel mix for own 4 output channels o = half*4 + j ----
    const int obase = half * 4;
    float Fr0[4], Fr1[4], Fi1[4], Fr2[4], Fi2[4];
    #pragma unroll
    for (int j = 0; j < 4; ++j) {
        const int o3 = (obase + j) * MM;
        float fr0 = 0.f, fr1 = 0.f, fi1 = 0.f, fr2 = 0.f, fi2 = 0.f;
        #pragma unroll
        for (int i = 0; i < 4; ++i) {       // input channels 0-3
            const int w3 = i * CC * MM + o3;
            const float w0 = s_wr[w3 + 0];
            const float w1r = s_wr[w3 + 1], w1i = s_wi[w3 + 1];
            const float w2r = s_wr[w3 + 2], w2i = s_wi[w3 + 2];
            fr0 += ALr0[i] * w0;
            fr1 += ALr1[i] * w1r - ALi1[i] * w1i;
            fi1 += ALr1[i] * w1i + ALi1[i] * w1r;
            fr2 += ALr2[i] * w2r - ALi2[i] * w2i;
            fi2 += ALr2[i] * w2i + ALi2[i] * w2r;
        }
        #pragma unroll
        for (int i = 0; i < 4; ++i) {       // input channels 4-7
            const int w3 = (i + 4) * CC * MM + o3;
            const float w0 = s_wr[w3 + 0];
            const float w1r = s_wr[w3 + 1], w1i = s_wi[w3 + 1];
            const float w2r = s_wr[w3 + 2], w2i = s_wi[w3 + 2];
            fr0 += AHr0[i] * w0;
            fr1 += AHr1[i] * w1r - AHi1[i] * w1i;
            fi1 += AHr1[i] * w1i + AHi1[i] * w1r;
            fr2 += AHr2[i] * w2r - AHi2[i] * w2i;
            fi2 += AHr2[i] * w2i + AHi2[i] * w2r;
        }
        Fr0[j] = fr0 * 0.0625f;   // 1/16 (DC); imag of DC dropped by irfft
        Fr1[j] = fr1 * 0.125f;    // 2/16 (modes 1,2)
        Fi1[j] = fi1 * 0.125f;
        Fr2[j] = fr2 * 0.125f;
        Fi2[j] = fi2 * 0.125f;
    }

    // ---- inverse + bf16 residual + store ----
    f4* __restrict__ op = out4 + g;
    #pragma unroll
    for (int t = 0; t < TT; ++t) {
        const float c1 = C1[t], s1 = S1[t], c2 = C2[t], s2 = S2[t];
        f4 r;
        #pragma unroll
        for (int j = 0; j < 4; ++j) {
            float yy = Fr0[j];
            yy += c1 * Fr1[j];
            yy -= s1 * Fi1[j];
            yy += c2 * Fr2[j];
            yy -= s2 * Fi2[j];
            const unsigned p = xb[t][j >> 1];
            const float xres = (j & 1) ? upHi(p) : upLo(p);
            r[j] = xres + yy;
        }
        op[(size_t)t * T4STRIDE] = r;
    }
}

extern "C" void kernel_launch(void* const* d_in, const int* in_sizes, int n_in,
                              void* d_out, int out_size, void* d_ws, size_t ws_size,
                              hipStream_t stream) {
    const f4* v4     = (const f4*)d_in[0];
    const float* wr  = (const float*)d_in[1];
    const float* wi  = (const float*)d_in[2];
    f4* out4 = (f4*)d_out;

    const int threads = 256;
    timeconvx_kernel<<<NBLK, threads, 0, stream>>>(v4, wr, wi, out4);
}